// Round 6
// baseline (21.497 us; speedup 1.0000x reference)
//
#include <hip/hip_runtime.h>
#include <hip/hip_bf16.h>
#include <math.h>

// HyperbolicDistanceHead: out[r][c] = -(2/sqrt(c))*atanh(clip(sqrt(c)*||mobius||,0,1-1e-5))
// B=128, C=4096, D=1024, c=0.5.
//  K1: x fp32 -> xb bf16 + exact fp32 x2[128] (tiny).
//  K2: 256 blocks x 512thr; block = 128 rows x 16 cols, BK=64 x 16 chunks.
//      Counted-vmcnt pipeline (T3/T4): 4 LDS buffers, 3 chunks in flight, raw
//      s_barrier + inline-asm waitcnt (never vmcnt(0) mid-loop). p fp32 read
//      once from HBM -> reg -> cvt bf16 -> LDS (p2 fused); x bf16 via
//      global_load_lds w=16 (source-side XOR swizzle, rule 21). Fully unrolled.

#define DDIM 1024
#define CDIM 4096
#define BDIM 128

using f32x2  = __attribute__((ext_vector_type(2))) float;
using f32x4  = __attribute__((ext_vector_type(4))) float;
using bf16x8 = __attribute__((ext_vector_type(8))) short;

#define GLOAD_LDS16(gp, lp) __builtin_amdgcn_global_load_lds(          \
    (const __attribute__((address_space(1))) void*)(gp),               \
    (__attribute__((address_space(3))) void*)(lp), 16, 0, 0)

#define VMCNT_(n) asm volatile("s_waitcnt vmcnt(" #n ")" ::: "memory")
#define VMCNT(n)  VMCNT_(n)
#define LGKM0     asm volatile("s_waitcnt lgkmcnt(0)" ::: "memory")
#define BARRIER   { __builtin_amdgcn_s_barrier(); __builtin_amdgcn_sched_barrier(0); }

__device__ inline ushort toBfU(float f) {
  __hip_bfloat16 h = __float2bfloat16(f);
  return *reinterpret_cast<ushort*>(&h);
}

// ---------------- K1: x -> bf16 + exact row sumsq ----------------
__global__ __launch_bounds__(256) void x_prep(
    const float* __restrict__ x, ushort* __restrict__ xb, float* __restrict__ x2) {
  __shared__ float part[4];
  const int tid = threadIdx.x, lane = tid & 63, w = tid >> 6;
  const int row = blockIdx.x;
  const f32x4 v = *(const f32x4*)(x + (size_t)row * DDIM + tid * 4);
  float a = v[0] * v[0];
  a = fmaf(v[1], v[1], a); a = fmaf(v[2], v[2], a); a = fmaf(v[3], v[3], a);
  ushort4 o = { toBfU(v[0]), toBfU(v[1]), toBfU(v[2]), toBfU(v[3]) };
  *(ushort4*)(xb + (size_t)row * DDIM + tid * 4) = o;
  #pragma unroll
  for (int off = 32; off > 0; off >>= 1) a += __shfl_xor(a, off, 64);
  if (lane == 0) part[w] = a;
  __syncthreads();
  if (tid == 0) x2[row] = part[0] + part[1] + part[2] + part[3];
}

// ---------------- K2: pipelined fused GEMM + epilogue ----------------
// Pipeline macros reference kernel-local vars; defined here textually.
//
// ISSUE(c, BUF, PV): p chunk c -> PV (f32x2); x chunk c -> xs[BUF] via 2 DMAs.
#define ISSUE(cn, BUF, PV)                                                    \
  {                                                                           \
    const int _c = (cn);                                                      \
    PV = *(const f32x2*)(pg + _c * 64);                                       \
    GLOAD_LDS16(xg0 + _c * 128, &xs[BUF][xl0]);                               \
    GLOAD_LDS16(xg1 + _c * 128, &xs[BUF][xl1]);                               \
  }
// COMPUTE(BUF): 2 MFMAs (k-halves) from xs/ps[BUF].
#define COMPUTE(BUF)                                                          \
  {                                                                           \
    const int off0 = (g << 4) ^ swr;                                          \
    const int off1 = (64 + (g << 4)) ^ swr;                                   \
    const bf16x8 a0 = *(const bf16x8*)&xs[BUF][arow * 128 + off0];            \
    const bf16x8 b0 = *(const bf16x8*)&ps[BUF][r15 * 128 + off0];             \
    acc = __builtin_amdgcn_mfma_f32_16x16x32_bf16(a0, b0, acc, 0, 0, 0);      \
    const bf16x8 a1 = *(const bf16x8*)&xs[BUF][arow * 128 + off1];            \
    const bf16x8 b1 = *(const bf16x8*)&ps[BUF][r15 * 128 + off1];             \
    acc = __builtin_amdgcn_mfma_f32_16x16x32_bf16(a1, b1, acc, 0, 0, 0);      \
  }
// WRITEP(BUF, PV): p2 accum + cvt + ds_write into ps[BUF].
#define WRITEP(BUF, PV)                                                       \
  {                                                                           \
    p2p = fmaf(PV[0], PV[0], p2p);                                            \
    p2p = fmaf(PV[1], PV[1], p2p);                                            \
    const unsigned pk = (unsigned)toBfU(PV[0]) | ((unsigned)toBfU(PV[1]) << 16); \
    *(unsigned*)&ps[BUF][pwb] = pk;                                           \
  }
#define ITER(cn, BI, PVI, BC, BW, PVW)                                        \
  {                                                                           \
    ISSUE((cn) + 3, BI, PVI);                                                 \
    COMPUTE(BC);                                                              \
    VMCNT(6);                                                                 \
    WRITEP(BW, PVW);                                                          \
    LGKM0; BARRIER;                                                           \
  }
#define ITER4(c4)                                                             \
  ITER((c4) + 0, 3, pv3, 0, 1, pv1)                                           \
  ITER((c4) + 1, 0, pv0, 1, 2, pv2)                                           \
  ITER((c4) + 2, 1, pv1, 2, 3, pv3)                                           \
  ITER((c4) + 3, 2, pv2, 3, 0, pv0)

__global__ __launch_bounds__(512) void hyper_fused(
    const ushort* __restrict__ xb, const float* __restrict__ p,
    const float* __restrict__ x2a, float* __restrict__ out) {
  __shared__ __align__(16) char xs[4][16384];   // [buf][128 rows][128 B]
  __shared__ __align__(16) char ps[4][2048];    // [buf][16 cols][128 B]
  __shared__ float p2t[16];

  const int tid  = threadIdx.x;
  const int lane = tid & 63;
  const int w    = __builtin_amdgcn_readfirstlane(tid >> 6);  // 0..7
  const int r15  = lane & 15, g = lane >> 4;
  const int swr  = (r15 & 7) << 4;
  const int arow = (w << 4) + r15;              // this wave's A rows = rows it stages

  // bijective XCD chunk swizzle (256 % 8 == 0)
  const int bid = blockIdx.x;
  const int swz = ((bid & 7) << 5) | (bid >> 3);
  const int cbase = swz * 16;

  // x staging (per wave, its own 16 rows): DMA j covers rows 16w+8j..+7.
  // LDS dest linear (base + lane*16); global source XOR-pre-swizzled (rule 21):
  // LDS[row][b] = G[row][b ^ ((row&7)<<4)], row&7 == lane>>3 here.
  const int xsw = ((lane & 7) << 4) ^ ((lane >> 3) << 4);
  const char* xg0 = (const char*)xb + (size_t)((w << 4) + (lane >> 3)) * 2048 + xsw;
  const char* xg1 = (const char*)xb + (size_t)((w << 4) + 8 + (lane >> 3)) * 2048 + xsw;
  const int xl0 = (w * 2) * 1024 + lane * 16;
  const int xl1 = (w * 2 + 1) * 1024 + lane * 16;

  // p staging: half-wave stages one col; lane covers k-pair (lane&31)*2.
  const int pcol = tid >> 5;                    // 0..15
  const float* pg = p + (size_t)(cbase + pcol) * DDIM + (lane & 31) * 2;
  const int pwb = pcol * 128 + (((lane & 31) << 2) ^ ((pcol & 7) << 4));

  f32x4 acc = {0.f, 0.f, 0.f, 0.f};
  float p2p = 0.f;
  f32x2 pv0, pv1, pv2, pv3;

  // ---- prologue: issue chunks 0..2; commit p0; enter steady state
  ISSUE(0, 0, pv0);
  ISSUE(1, 1, pv1);
  ISSUE(2, 2, pv2);
  VMCNT(6);            // chunk 0 arrived (p0 reg + x0 DMA); 1,2 in flight
  WRITEP(0, pv0);
  LGKM0; BARRIER;

  // ---- main: chunks 0..11, 3 in flight, one raw barrier per chunk
  ITER4(0)
  ITER4(4)
  ITER4(8)

  // ---- tail: chunks 12..15, draining
  ISSUE(15, 3, pv3);
  COMPUTE(0);          // chunk 12
  VMCNT(6);            // chunk 13 arrived
  WRITEP(1, pv1);
  LGKM0; BARRIER;

  COMPUTE(1);          // chunk 13
  VMCNT(3);            // chunk 14 arrived
  WRITEP(2, pv2);
  LGKM0; BARRIER;

  COMPUTE(2);          // chunk 14
  VMCNT(0);            // chunk 15 arrived
  WRITEP(3, pv3);
  LGKM0; BARRIER;

  COMPUTE(3);          // chunk 15

  // ---- p2 reduce within each 32-lane half (col = tid>>5)
  p2p += __shfl_xor(p2p, 16, 64);
  p2p += __shfl_xor(p2p, 8, 64);
  p2p += __shfl_xor(p2p, 4, 64);
  p2p += __shfl_xor(p2p, 2, 64);
  p2p += __shfl_xor(p2p, 1, 64);
  if ((lane & 31) == 0) p2t[pcol] = p2p;
  __syncthreads();

  // ---- epilogue: closed-form Poincare distance, c = 0.5
  const float p2 = p2t[r15];
  #pragma unroll
  for (int i = 0; i < 4; ++i) {
    // C-frag: col = lane&15, row = (lane>>4)*4 + i (verified m89 mapping)
    const int  row = (w << 4) + (g << 2) + i;
    const float dot = acc[i];                          // <x,p>; mdot = -dot
    const float x2  = x2a[row];
    const float A   = 1.0f - dot + 0.5f  * p2;         // 1 + 2c*mdot + c*p2
    const float Bc  = 1.0f - 0.5f * x2;                // 1 - c*x2
    const float den = 1.0f - dot + 0.25f * x2 * p2;    // 1 + 2c*mdot + c^2*x2*p2
    float num2 = A * A * x2 - 2.0f * A * Bc * dot + Bc * Bc * p2;
    float m2   = fmaxf(num2, 0.0f) / fmaxf(den * den, 1e-15f);
    float arg  = fminf(0.7071067811865476f * sqrtf(m2 + 1e-15f), 0.99999f);
    out[(size_t)row * CDIM + cbase + r15] =
        -1.4142135623730951f * __logf((1.0f + arg) / (1.0f - arg));
  }
}

extern "C" void kernel_launch(void* const* d_in, const int* in_sizes, int n_in,
                              void* d_out, int out_size, void* d_ws, size_t ws_size,
                              hipStream_t stream) {
  const float* x = (const float*)d_in[0];   // [128,1024] fp32
  const float* p = (const float*)d_in[1];   // [4096,1024] fp32
  float* out = (float*)d_out;               // [128,4096] fp32

  // ws: xb[128*1024] bf16 | x2[128] f32 (262656 B; harness ws >= 8.6 MB)
  ushort* xb = (ushort*)d_ws;
  float*  x2 = (float*)((char*)d_ws + (size_t)BDIM * DDIM * 2);

  x_prep<<<dim3(BDIM), dim3(256), 0, stream>>>(x, xb, x2);
  hyper_fused<<<dim3(256), dim3(512), 0, stream>>>(xb, p, x2, out);
}

// Round 7
// 13.317 us; speedup vs baseline: 1.6143x; 1.6143x over previous
//
#include <hip/hip_runtime.h>
#include <hip/hip_bf16.h>
#include <math.h>

// HyperbolicDistanceHead: out[r][c] = -(2/sqrt(c))*atanh(clip(sqrt(c)*||mobius(-x,p)||, 0, 1-1e-5))
// B=128, C=4096, D=1024, c=0.5.
// Single kernel, no workspace. 512 blocks x 256 thr (4 waves); block = 64 rows x 16 cols;
// wave = 16x16 output, full K (no cross-wave combine) -> 2 independent blocks/CU.
// Both operands reg-staged fp32 -> cvt bf16 -> XOR-swizzled LDS (write+read swizzled,
// rule 21); BK=128 x 8 chunks, double-buffered, one __syncthreads per chunk, T14
// issue-early/write-late. x2/p2 from pre-cvt fp32, 16-lane shfl reduce.

#define DDIM 1024
#define CDIM 4096

using f32x4  = __attribute__((ext_vector_type(4))) float;
using bf16x8 = __attribute__((ext_vector_type(8))) short;

__device__ inline ushort toBfU(float f) {
  __hip_bfloat16 h = __float2bfloat16(f);
  return *reinterpret_cast<ushort*>(&h);
}

__global__ __launch_bounds__(256) void hyper_one(
    const float* __restrict__ x, const float* __restrict__ p, float* __restrict__ out) {
  __shared__ __align__(16) char xs[2][64 * 256];   // 32 KB: [buf][row][256 B = 128 bf16]
  __shared__ __align__(16) char ps[2][16 * 256];   // 8 KB:  [buf][col][256 B]
  __shared__ float x2s[64];
  __shared__ float p2s[16];

  const int tid  = threadIdx.x;
  const int lane = tid & 63;
  const int w    = __builtin_amdgcn_readfirstlane(tid >> 6);  // 0..3
  const int r15  = lane & 15, g = lane >> 4;

  // bijective XCD chunk swizzle (512 % 8 == 0): XCD owns 32 colgroups x both rowgroups
  const int bid = blockIdx.x;
  const int swz = ((bid & 7) << 6) | (bid >> 3);
  const int cg = swz >> 1, rg = swz & 1;
  const int rbase = rg * 64, cbase = cg * 16;

  // ---- staging maps (per chunk c, k-offset = c*128 floats)
  const int t16 = tid & 15;            // k-slot: floats t16*8 .. +7
  const int tr  = tid >> 4;            // 0..15: x seg-row / p col
  const float* gx = x + (size_t)(rbase + tr) * DDIM + t16 * 8;  // seg i: + i*16*DDIM
  const float* gp = p + (size_t)(cbase + tr) * DDIM + t16 * 8;

  int xw[4];
  #pragma unroll
  for (int i = 0; i < 4; ++i) {
    const int row = i * 16 + tr;
    xw[i] = row * 256 + ((t16 ^ (row & 7)) << 4);
  }
  const int pw = tr * 256 + ((t16 ^ (tr & 7)) << 4);

  f32x4 xa[4][2], pa[2];
  float s0 = 0.f, s1 = 0.f, s2 = 0.f, s3 = 0.f, p2p = 0.f;
  f32x4 acc = {0.f, 0.f, 0.f, 0.f};

  // A/B rows this wave reads (A row = 16w + r15 -> row&7 == r15&7)
  const int arow = (w << 4) + r15;

#define ISSUE(c)                                                               \
  {                                                                            \
    const int ko = (c) * 128;                                                  \
    _Pragma("unroll")                                                          \
    for (int i = 0; i < 4; ++i) {                                              \
      xa[i][0] = *(const f32x4*)(gx + (size_t)i * 16 * DDIM + ko);             \
      xa[i][1] = *(const f32x4*)(gx + (size_t)i * 16 * DDIM + ko + 4);         \
    }                                                                          \
    pa[0] = *(const f32x4*)(gp + ko);                                          \
    pa[1] = *(const f32x4*)(gp + ko + 4);                                      \
  }

#define SSQ(v, s)                                                              \
  { s = fmaf(v[0], v[0], s); s = fmaf(v[1], v[1], s);                          \
    s = fmaf(v[2], v[2], s); s = fmaf(v[3], v[3], s); }

#define PACK8(a, b, dst)                                                       \
  { bf16x8 _t;                                                                 \
    _t[0] = (short)toBfU(a[0]); _t[1] = (short)toBfU(a[1]);                    \
    _t[2] = (short)toBfU(a[2]); _t[3] = (short)toBfU(a[3]);                    \
    _t[4] = (short)toBfU(b[0]); _t[5] = (short)toBfU(b[1]);                    \
    _t[6] = (short)toBfU(b[2]); _t[7] = (short)toBfU(b[3]);                    \
    *(bf16x8*)(dst) = _t; }

#define WRITE(buf)                                                             \
  {                                                                            \
    SSQ(xa[0][0], s0) SSQ(xa[0][1], s0)                                        \
    SSQ(xa[1][0], s1) SSQ(xa[1][1], s1)                                        \
    SSQ(xa[2][0], s2) SSQ(xa[2][1], s2)                                        \
    SSQ(xa[3][0], s3) SSQ(xa[3][1], s3)                                        \
    SSQ(pa[0], p2p)   SSQ(pa[1], p2p)                                          \
    PACK8(xa[0][0], xa[0][1], &xs[buf][xw[0]])                                 \
    PACK8(xa[1][0], xa[1][1], &xs[buf][xw[1]])                                 \
    PACK8(xa[2][0], xa[2][1], &xs[buf][xw[2]])                                 \
    PACK8(xa[3][0], xa[3][1], &xs[buf][xw[3]])                                 \
    PACK8(pa[0], pa[1], &ps[buf][pw])                                          \
  }

#define COMPUTE(buf)                                                           \
  {                                                                            \
    _Pragma("unroll")                                                          \
    for (int ks = 0; ks < 4; ++ks) {                                           \
      const int off = ((ks * 4 + g) ^ (r15 & 7)) << 4;                         \
      const bf16x8 a = *(const bf16x8*)&xs[buf][arow * 256 + off];             \
      const bf16x8 b = *(const bf16x8*)&ps[buf][r15 * 256 + off];              \
      acc = __builtin_amdgcn_mfma_f32_16x16x32_bf16(a, b, acc, 0, 0, 0);       \
    }                                                                          \
  }

  // ---- prologue: chunk 0 -> buf 0
  ISSUE(0)
  WRITE(0)

  // ---- main: 8 chunks, 1 barrier each; issue-early, write-late (T14)
  #pragma unroll
  for (int c = 0; c < 8; ++c) {
    __syncthreads();                  // publish buf(c&1); frees buf^1 for overwrite
    if (c < 7) ISSUE(c + 1)
    COMPUTE(c & 1)
    if (c < 7) WRITE((c + 1) & 1)
  }

  // ---- norm reduces: 16-lane groups (same row/col), leaders -> LDS
  #pragma unroll
  for (int off = 8; off > 0; off >>= 1) {
    s0 += __shfl_xor(s0, off, 64);
    s1 += __shfl_xor(s1, off, 64);
    s2 += __shfl_xor(s2, off, 64);
    s3 += __shfl_xor(s3, off, 64);
    p2p += __shfl_xor(p2p, off, 64);
  }
  if ((lane & 15) == 0) {
    x2s[0 * 16 + tr] = s0;
    x2s[1 * 16 + tr] = s1;
    x2s[2 * 16 + tr] = s2;
    x2s[3 * 16 + tr] = s3;
    p2s[tr] = p2p;
  }
  __syncthreads();

  // ---- epilogue: closed-form Poincare distance, c = 0.5
  const float p2 = p2s[r15];
  #pragma unroll
  for (int i = 0; i < 4; ++i) {
    // C-frag: col = lane&15, row = (lane>>4)*4 + i (verified m89 mapping)
    const int  rloc = (w << 4) + (g << 2) + i;    // block-local row
    const float dot = acc[i];                     // <x,p>; mdot = -dot
    const float x2  = x2s[rloc];
    const float A   = 1.0f - dot + 0.5f  * p2;    // 1 + 2c*mdot + c*p2
    const float Bc  = 1.0f - 0.5f * x2;           // 1 - c*x2
    const float den = 1.0f - dot + 0.25f * x2 * p2;
    float num2 = A * A * x2 - 2.0f * A * Bc * dot + Bc * Bc * p2;
    float m2   = fmaxf(num2, 0.0f) / fmaxf(den * den, 1e-15f);
    float arg  = fminf(0.7071067811865476f * sqrtf(m2 + 1e-15f), 0.99999f);
    out[(size_t)(rbase + rloc) * CDIM + cbase + r15] =
        -1.4142135623730951f * __logf((1.0f + arg) / (1.0f - arg));
  }
}

extern "C" void kernel_launch(void* const* d_in, const int* in_sizes, int n_in,
                              void* d_out, int out_size, void* d_ws, size_t ws_size,
                              hipStream_t stream) {
  const float* x = (const float*)d_in[0];   // [128,1024] fp32
  const float* p = (const float*)d_in[1];   // [4096,1024] fp32
  float* out = (float*)d_out;               // [128,4096] fp32
  hyper_one<<<dim3(512), dim3(256), 0, stream>>>(x, p, out);
}